// Round 10
// baseline (2306.517 us; speedup 1.0000x reference)
//
#include <hip/hip_runtime.h>

typedef __bf16 bhalf;
typedef __bf16 bh8_t __attribute__((ext_vector_type(8)));
typedef float f4_t __attribute__((ext_vector_type(4)));

#define MFMA16(A, B, C) __builtin_amdgcn_mfma_f32_16x16x32_bf16((A), (B), (C), 0, 0, 0)

// Problem: B=32768, D_IN=128, H=1024, N_FLUX=512, N_MET=256, N_IN=128
//
// ROUND 10: r9 was latency-bound: 1 block/CU (124 KB LDS) -> 8 waves in ONE
// lockstep barrier group; every vmcnt/ds_read/barrier stall unhidden (MfmaUtil
// 18%, LDS pipe only ~25% busy). Fix: LDS = exactly 80 KB -> 2 blocks/CU =
// 16 waves/CU in TWO independent barrier groups; single-buffered staging
// (cross-block overlap replaces intra-block double-buffer). V/R arrays get
// power-of-2 strides + XOR swizzle (chunk ^= rot3(row&7)) for bank spread.

#define OFF_W1T  0
#define OFF_W2T  (OFF_W1T + 1024 * 128)
#define OFF_PINB (OFF_W2T + 512 * 1024)
#define OFF_PT   (OFF_PINB + 128 * 512)
#define OFF_G    (OFF_PT + 512 * 128)

__global__ __launch_bounds__(256) void amn_prep(
    const float* __restrict__ W1, const float* __restrict__ W2,
    const float* __restrict__ Pin, bhalf* __restrict__ ws) {
  unsigned i = blockIdx.x * 256u + threadIdx.x;
  if (i < 131072u) {                   // W1t[n][k] = W1[k][n]
    unsigned n = i >> 7, k = i & 127u;
    ws[OFF_W1T + i] = (bhalf)W1[k * 1024u + n];
  } else if (i < 655360u) {            // W2t[n][k] = W2[k][n]
    unsigned j = i - 131072u;
    unsigned n = j >> 10, k = j & 1023u;
    ws[OFF_W2T + j] = (bhalf)W2[k * 512u + n];
  } else if (i < 720896u) {            // Pinb = bf16(Pin)
    unsigned j = i - 655360u;
    ws[OFF_PINB + j] = (bhalf)Pin[j];
  } else if (i < 786432u) {            // Pt[n][k] = Pin[k][n] * 2/128
    unsigned j = i - 720896u;
    unsigned n = j >> 7, k = j & 127u;
    ws[OFF_PT + j] = (bhalf)(Pin[k * 512u + n] * 0.015625f);
  }
}

// G[i][j] = (2/256) * sum_k S[k][i]*S[k][j]
__global__ __launch_bounds__(256) void amn_gram(
    const float* __restrict__ S, bhalf* __restrict__ ws) {
  const unsigned bi = blockIdx.x >> 5, bj = blockIdx.x & 31u;
  __shared__ float SA[256][16];
  __shared__ float SB[256][16];
  const unsigned t = threadIdx.x;
#pragma unroll
  for (int p = 0; p < 16; ++p) {
    unsigned e = p * 256u + t;
    unsigned k = e >> 4, c = e & 15u;
    SA[k][c] = S[k * 512u + bi * 16u + c];
    SB[k][c] = S[k * 512u + bj * 16u + c];
  }
  __syncthreads();
  const unsigned ti = t >> 4, tj = t & 15u;
  float acc = 0.f;
#pragma unroll 8
  for (int k = 0; k < 256; ++k) acc += SA[k][ti] * SB[k][tj];
  ws[OFF_G + (bi * 16u + ti) * 512u + bj * 16u + tj] = (bhalf)(acc * 0.0078125f);
}

__device__ inline bh8_t cvt8(f4_t f0, f4_t f1) {
  bh8_t r;
  r[0] = (bhalf)f0[0]; r[1] = (bhalf)f0[1]; r[2] = (bhalf)f0[2]; r[3] = (bhalf)f0[3];
  r[4] = (bhalf)f1[0]; r[5] = (bhalf)f1[1]; r[6] = (bhalf)f1[2]; r[7] = (bhalf)f1[3];
  return r;
}
__device__ inline unsigned pk2(float a, float b) {
  union { bhalf h; unsigned short s; } x, y;
  x.h = (bhalf)a; y.h = (bhalf)b;
  return (unsigned)x.s | ((unsigned)y.s << 16);
}
__device__ inline float up_lo(unsigned u) {
  union { unsigned u; float f; } t; t.u = u << 16; return t.f;
}
__device__ inline float up_hi(unsigned u) {
  union { unsigned u; float f; } t; t.u = u & 0xffff0000u; return t.f;
}
// bit-rotated row swizzle: adjacent rows land in different bank quads
__device__ inline unsigned rot3(unsigned r) { return ((r & 1u) << 2) | ((r >> 1) & 3u); }

__device__ inline void gload16(const void* g, void* l) {
  __builtin_amdgcn_global_load_lds(
      (const __attribute__((address_space(1))) void*)g,
      (__attribute__((address_space(3))) void*)l, 16, 0, 0);
}

// LDS (bytes, total 81,920 = exactly 2 blocks/CU):
//   V  [32][512] bf16 swizzled @ 0      (32,768)
//   R  [32][128] bf16 swizzled @ 32768  ( 8,192)
//   Gbuf (1 chunk: 512 rows x 32 k)     @ 40960  (32,768)
//   Pbuf (1 chunk: 128 rows x 32 k)     @ 73728  ( 8,192)
//   hid [32][1032] bf16 @ 0 (66,048; MLP phase only, aliases V/R/Gbuf)
#define SMV   0
#define SMR   32768
#define SMB   40960
#define SMP   73728
#define SMEM_BYTES 81920

__global__ __launch_bounds__(512) void amn_main(
    const float* __restrict__ input, const float* __restrict__ Vin,
    const float* __restrict__ b1, const float* __restrict__ b2,
    const int* __restrict__ niter_p,
    const bhalf* __restrict__ ws, float* __restrict__ out) {

  const unsigned tid = threadIdx.x;
  const unsigned w  = tid >> 6;    // wave 0..7
  const unsigned l  = tid & 63u;
  const unsigned lq = l >> 4;      // 0..3
  const unsigned lr = l & 15u;     // 0..15
  const unsigned row0 = blockIdx.x * 32u;
  const unsigned rq  = l >> 2;         // staging: row-in-seg 0..15
  const unsigned c16 = (l & 3u) * 16u; // staging: byte-in-row

  const bhalf* W1t = ws + OFF_W1T;
  const bhalf* W2t = ws + OFF_W2T;

  __shared__ __align__(16) unsigned char smem[SMEM_BYTES];
  bhalf* hid_lds = (bhalf*)smem;  // [32][1032], MLP only

  // ===== MLP1: hidden = relu(input @ W1 + b1); wave w owns tiles 8w..8w+7 =====
  {
    f4_t hacc[2][8];
#pragma unroll
    for (int mt = 0; mt < 2; ++mt)
#pragma unroll
      for (int t = 0; t < 8; ++t) hacc[mt][t] = (f4_t)0.f;

#pragma unroll
    for (int k = 0; k < 4; ++k) {   // K = 128
      bh8_t a[2];
#pragma unroll
      for (int mt = 0; mt < 2; ++mt) {
        const float* ap = input + (row0 + 16u * mt + lr) * 128u + k * 32 + lq * 8u;
        a[mt] = cvt8(*(const f4_t*)ap, *(const f4_t*)(ap + 4));
      }
#pragma unroll
      for (int t = 0; t < 8; ++t) {
        bh8_t b = *(const bh8_t*)(W1t + (16u * (8u * w + t) + lr) * 128u + k * 32 + lq * 8u);
#pragma unroll
        for (int mt = 0; mt < 2; ++mt) hacc[mt][t] = MFMA16(a[mt], b, hacc[mt][t]);
      }
    }
#pragma unroll
    for (int t = 0; t < 8; ++t) {
      unsigned col = 16u * (8u * w + t) + lr;
      float bias = b1[col];
#pragma unroll
      for (int mt = 0; mt < 2; ++mt)
#pragma unroll
        for (int r = 0; r < 4; ++r)
          hid_lds[(16u * mt + 4u * lq + r) * 1032u + col] =
              (bhalf)fmaxf(hacc[mt][t][r] + bias, 0.f);
    }
  }
  __syncthreads();

  // ===== MLP2: V0 = hidden @ W2 + b2; wave w owns V n-tiles 4w..4w+3 =====
  f4_t Vreg[2][4];
#pragma unroll
  for (int mt = 0; mt < 2; ++mt)
#pragma unroll
    for (int n = 0; n < 4; ++n) Vreg[mt][n] = (f4_t)0.f;

#pragma unroll 2
  for (int k = 0; k < 32; ++k) {  // K = 1024
    bh8_t a[2];
#pragma unroll
    for (int mt = 0; mt < 2; ++mt)
      a[mt] = *(const bh8_t*)(hid_lds + (16u * mt + lr) * 1032u + k * 32 + lq * 8u);
#pragma unroll
    for (int n = 0; n < 4; ++n) {
      bh8_t b = *(const bh8_t*)(W2t + (16u * (4u * w + n) + lr) * 1024u + k * 32 + lq * 8u);
#pragma unroll
      for (int mt = 0; mt < 2; ++mt) Vreg[mt][n] = MFMA16(a[mt], b, Vreg[mt][n]);
    }
  }
#pragma unroll
  for (int n = 0; n < 4; ++n) {
    float bias = b2[16u * (4u * w + n) + lr];
#pragma unroll
    for (int mt = 0; mt < 2; ++mt)
#pragma unroll
      for (int r = 0; r < 4; ++r) Vreg[mt][n][r] += bias;
  }

  // ---- Vin for u-tile w, packed bf16: 4 regs ----
  unsigned Vinpk[2][2];
#pragma unroll
  for (int mt = 0; mt < 2; ++mt) {
    float vi[4];
#pragma unroll
    for (int r = 0; r < 4; ++r)
      vi[r] = Vin[(row0 + 16u * mt + 4u * lq + r) * 128u + 16u * w + lr];
    Vinpk[mt][0] = pk2(vi[0], vi[1]);
    Vinpk[mt][1] = pk2(vi[2], vi[3]);
  }

  // ---- diff state, packed bf16: 16 regs ----
  unsigned Dpk[2][4][2];
#pragma unroll
  for (int mt = 0; mt < 2; ++mt)
#pragma unroll
    for (int n = 0; n < 4; ++n) { Dpk[mt][n][0] = 0u; Dpk[mt][n][1] = 0u; }

  const int niter = niter_p[0];

  asm volatile("s_waitcnt vmcnt(0)" ::: "memory");  // exact manual counting below
  __syncthreads();  // hid reads done; V/R/G/P regions reusable

  const char* Gb  = (const char*)(ws + OFF_G);
  const char* Pb  = (const char*)(ws + OFF_PINB);
  const char* Ptb = (const char*)(ws + OFF_PT);

  // ================= 30 momentum iterations =================
  for (int it = 0; it < niter; ++it) {
    // ---- (i) stage V (bf16, swizzled [32][512]) ----
#pragma unroll
    for (int mt = 0; mt < 2; ++mt)
#pragma unroll
      for (int n = 0; n < 4; ++n) {
        unsigned chunk0 = 2u * (4u * w + n) + (lr >> 3);
        unsigned wi = (lr & 7u) * 2u;
#pragma unroll
        for (int r = 0; r < 4; ++r) {
          unsigned row = 16u * mt + 4u * lq + r;
          *(bhalf*)(smem + SMV + row * 1024u +
                    ((chunk0 ^ rot3(row & 7u)) << 4) + wi) = (bhalf)Vreg[mt][n][r];
        }
      }
    asm volatile("s_waitcnt lgkmcnt(0)" ::: "memory");

    // prologue: stage G chunk 0 + P chunk 0 (5 loads/wave)
#pragma unroll
    for (int i = 0; i < 4; ++i) {
      unsigned s = w + 8u * i;
      gload16(Gb + ((16u * s + rq) * 512u) * 2u + c16, smem + SMB + s * 1024u);
    }
    gload16(Pb + ((16u * w + rq) * 512u) * 2u + c16, smem + SMP + w * 1024u);
    asm volatile("s_waitcnt vmcnt(0)" ::: "memory");
    __builtin_amdgcn_s_barrier();     // V staged + chunk 0 valid
    __builtin_amdgcn_sched_barrier(0);

    f4_t dacc[4][2];
#pragma unroll
    for (int nt = 0; nt < 4; ++nt) { dacc[nt][0] = (f4_t)0.f; dacc[nt][1] = (f4_t)0.f; }
    f4_t Uacc[2];
    Uacc[0] = (f4_t)0.f; Uacc[1] = (f4_t)0.f;

    // ---- fused (ii)+(iii-G): per chunk t: dacc += V@G, Uacc += V@Pin^T ----
#pragma unroll 1
    for (int t = 0; t < 16; ++t) {
      // compute on chunk t
      {
        unsigned vph = (((unsigned)(4 * t) + lq) ^ rot3(lr & 7u)) << 4;
        bh8_t a0 = *(const bh8_t*)(smem + SMV + lr * 1024u + vph);
        bh8_t a1 = *(const bh8_t*)(smem + SMV + (16u + lr) * 1024u + vph);
        const bhalf* gb = (const bhalf*)(smem + SMB);
        const bhalf* pb = (const bhalf*)(smem + SMP);
#pragma unroll
        for (int nt = 0; nt < 4; ++nt) {
          bh8_t bfr = *(const bh8_t*)(gb + (16u * (4u * w + nt) + lr) * 32u + lq * 8u);
          dacc[nt][0] = MFMA16(a0, bfr, dacc[nt][0]);
          dacc[nt][1] = MFMA16(a1, bfr, dacc[nt][1]);
        }
        bh8_t pf = *(const bh8_t*)(pb + (16u * w + lr) * 32u + lq * 8u);
        Uacc[0] = MFMA16(a0, pf, Uacc[0]);
        Uacc[1] = MFMA16(a1, pf, Uacc[1]);
      }
      asm volatile("s_waitcnt lgkmcnt(0)" ::: "memory");
      __builtin_amdgcn_s_barrier();    // all waves done reading buffer
      __builtin_amdgcn_sched_barrier(0);

      if (t < 15) {
        unsigned u = (unsigned)t + 1u;
#pragma unroll
        for (int i = 0; i < 4; ++i) {
          unsigned s = w + 8u * i;
          gload16(Gb + ((16u * s + rq) * 512u + u * 32u) * 2u + c16, smem + SMB + s * 1024u);
        }
        gload16(Pb + ((16u * w + rq) * 512u + u * 32u) * 2u + c16, smem + SMP + w * 1024u);
        asm volatile("s_waitcnt vmcnt(0)" ::: "memory");
      } else {
        // stage Pt chunk 0 into G buffer; overlap with R write
#pragma unroll
        for (int i = 0; i < 4; ++i) {
          unsigned s = w + 8u * i;
          gload16(Ptb + ((16u * s + rq) * 128u) * 2u + c16, smem + SMB + s * 1024u);
        }
        // R = relu(U - Vin) -> LDS (swizzled [32][128])
#pragma unroll
        for (int mt = 0; mt < 2; ++mt) {
          float v0 = up_lo(Vinpk[mt][0]), v1 = up_hi(Vinpk[mt][0]);
          float v2 = up_lo(Vinpk[mt][1]), v3 = up_hi(Vinpk[mt][1]);
          float rv[4] = { fmaxf(Uacc[mt][0] - v0, 0.f), fmaxf(Uacc[mt][1] - v1, 0.f),
                          fmaxf(Uacc[mt][2] - v2, 0.f), fmaxf(Uacc[mt][3] - v3, 0.f) };
          unsigned chunk0 = 2u * w + (lr >> 3);
          unsigned wi = (lr & 7u) * 2u;
#pragma unroll
          for (int r = 0; r < 4; ++r) {
            unsigned row = 16u * mt + 4u * lq + r;
            *(bhalf*)(smem + SMR + row * 256u +
                      ((chunk0 ^ rot3(row & 7u)) << 4) + wi) = (bhalf)rv[r];
          }
        }
        asm volatile("s_waitcnt vmcnt(0) lgkmcnt(0)" ::: "memory");
      }
      __builtin_amdgcn_s_barrier();    // new chunk valid (and R visible at t==15)
      __builtin_amdgcn_sched_barrier(0);
    }

    // ---- (iii-Pt): dacc += R @ Pt, 4 staged chunks, single-buffered ----
#pragma unroll 1
    for (int t2 = 0; t2 < 4; ++t2) {
      {
        unsigned rph = (((unsigned)(4 * t2) + lq) ^ rot3(lr & 7u)) << 4;
        bh8_t a0 = *(const bh8_t*)(smem + SMR + lr * 256u + rph);
        bh8_t a1 = *(const bh8_t*)(smem + SMR + (16u + lr) * 256u + rph);
        const bhalf* gb = (const bhalf*)(smem + SMB);
#pragma unroll
        for (int nt = 0; nt < 4; ++nt) {
          bh8_t bfr = *(const bh8_t*)(gb + (16u * (4u * w + nt) + lr) * 32u + lq * 8u);
          dacc[nt][0] = MFMA16(a0, bfr, dacc[nt][0]);
          dacc[nt][1] = MFMA16(a1, bfr, dacc[nt][1]);
        }
      }
      asm volatile("s_waitcnt lgkmcnt(0)" ::: "memory");
      __builtin_amdgcn_s_barrier();
      __builtin_amdgcn_sched_barrier(0);
      if (t2 < 3) {
        unsigned kc = (unsigned)t2 + 1u;
#pragma unroll
        for (int i = 0; i < 4; ++i) {
          unsigned s = w + 8u * i;
          gload16(Ptb + ((16u * s + rq) * 128u + kc * 32u) * 2u + c16, smem + SMB + s * 1024u);
        }
        asm volatile("s_waitcnt vmcnt(0)" ::: "memory");
        __builtin_amdgcn_s_barrier();
        __builtin_amdgcn_sched_barrier(0);
      }
    }

    // ---- momentum update: dV += min(V,0)*2/512; d = .9d - .01dV; V += d ----
#pragma unroll
    for (int nt = 0; nt < 4; ++nt)
#pragma unroll
      for (int mt = 0; mt < 2; ++mt) {
        float dv0 = dacc[nt][mt][0] + fminf(Vreg[mt][nt][0], 0.f) * 0.00390625f;
        float dv1 = dacc[nt][mt][1] + fminf(Vreg[mt][nt][1], 0.f) * 0.00390625f;
        float dv2 = dacc[nt][mt][2] + fminf(Vreg[mt][nt][2], 0.f) * 0.00390625f;
        float dv3 = dacc[nt][mt][3] + fminf(Vreg[mt][nt][3], 0.f) * 0.00390625f;
        float d0 = 0.9f * up_lo(Dpk[mt][nt][0]) - 0.01f * dv0;
        float d1 = 0.9f * up_hi(Dpk[mt][nt][0]) - 0.01f * dv1;
        float d2 = 0.9f * up_lo(Dpk[mt][nt][1]) - 0.01f * dv2;
        float d3 = 0.9f * up_hi(Dpk[mt][nt][1]) - 0.01f * dv3;
        Vreg[mt][nt][0] += d0; Vreg[mt][nt][1] += d1;
        Vreg[mt][nt][2] += d2; Vreg[mt][nt][3] += d3;
        Dpk[mt][nt][0] = pk2(d0, d1);
        Dpk[mt][nt][1] = pk2(d2, d3);
      }
  }

  // ---- write final V ----
#pragma unroll
  for (int mt = 0; mt < 2; ++mt)
#pragma unroll
    for (int n = 0; n < 4; ++n) {
      unsigned col = 16u * (4u * w + n) + lr;
#pragma unroll
      for (int r = 0; r < 4; ++r)
        out[(row0 + 16u * mt + 4u * lq + r) * 512u + col] = Vreg[mt][n][r];
    }
}

extern "C" void kernel_launch(void* const* d_in, const int* in_sizes, int n_in,
                              void* d_out, int out_size, void* d_ws, size_t ws_size,
                              hipStream_t stream) {
  const float* input = (const float*)d_in[0];
  // d_in[1] = Vref (unused by reference)
  const float* Vin = (const float*)d_in[2];
  const float* W1  = (const float*)d_in[3];
  const float* b1  = (const float*)d_in[4];
  const float* W2  = (const float*)d_in[5];
  const float* b2  = (const float*)d_in[6];
  const float* S   = (const float*)d_in[7];
  const float* Pin = (const float*)d_in[8];
  const int* nit   = (const int*)d_in[9];
  bhalf* ws  = (bhalf*)d_ws;
  float* out = (float*)d_out;

  amn_prep<<<3072, 256, 0, stream>>>(W1, W2, Pin, ws);
  amn_gram<<<1024, 256, 0, stream>>>(S, ws);
  amn_main<<<1024, 512, 0, stream>>>(input, Vin, b1, b2, nit, ws, out);
}

// Round 12
// 1694.962 us; speedup vs baseline: 1.3608x; 1.3608x over previous
//
#include <hip/hip_runtime.h>

typedef __bf16 bhalf;
typedef __bf16 bh8_t __attribute__((ext_vector_type(8)));
typedef float f4_t __attribute__((ext_vector_type(4)));

#define MFMA16(A, B, C) __builtin_amdgcn_mfma_f32_16x16x32_bf16((A), (B), (C), 0, 0, 0)

// Problem: B=32768, D_IN=128, H=1024, N_FLUX=512, N_MET=256, N_IN=128
//
// ROUND 12: r9 skeleton (PASSED, 1721us) + ONE schedule change: 1 barrier per
// chunk (was 2), 3-buffer distance-2 pipeline: {VMW(own); s_barrier; compute t;
// lgkmcnt0; issue t+2}. Cross-wave staging (r9's s=w+8i) kept; V layout linear
// 520 (r9-proven); R linear-128 in buf2's P-region with additive col-rotation
// (col+8*row)&127 (8-aligned groups never wrap; 2-way banks). Pipeline drains
// to 0 each iteration (no cross-iteration in-flight - r11's failed gamble).
// vmcnt ledger: steps0-14 enter@10->VMW(5); 15@9->VMW(4); 16-18@8->VMW(4);
// 19@4->VMW(0). BAR_B required: Pt3@buf1 (step19, post-barrier read) vs next
// iter's chunk-1 DMA into buf1.

#define OFF_W1T  0
#define OFF_W2T  (OFF_W1T + 1024 * 128)
#define OFF_PINB (OFF_W2T + 512 * 1024)
#define OFF_PT   (OFF_PINB + 128 * 512)
#define OFF_G    (OFF_PT + 512 * 128)

__global__ __launch_bounds__(256) void amn_prep(
    const float* __restrict__ W1, const float* __restrict__ W2,
    const float* __restrict__ Pin, bhalf* __restrict__ ws) {
  unsigned i = blockIdx.x * 256u + threadIdx.x;
  if (i < 131072u) {                   // W1t[n][k] = W1[k][n]
    unsigned n = i >> 7, k = i & 127u;
    ws[OFF_W1T + i] = (bhalf)W1[k * 1024u + n];
  } else if (i < 655360u) {            // W2t[n][k] = W2[k][n]
    unsigned j = i - 131072u;
    unsigned n = j >> 10, k = j & 1023u;
    ws[OFF_W2T + j] = (bhalf)W2[k * 512u + n];
  } else if (i < 720896u) {            // Pinb = bf16(Pin)
    unsigned j = i - 655360u;
    ws[OFF_PINB + j] = (bhalf)Pin[j];
  } else if (i < 786432u) {            // Pt[n][k] = Pin[k][n] * 2/128
    unsigned j = i - 720896u;
    unsigned n = j >> 7, k = j & 127u;
    ws[OFF_PT + j] = (bhalf)(Pin[k * 512u + n] * 0.015625f);
  }
}

// G[i][j] = (2/256) * sum_k S[k][i]*S[k][j]
__global__ __launch_bounds__(256) void amn_gram(
    const float* __restrict__ S, bhalf* __restrict__ ws) {
  const unsigned bi = blockIdx.x >> 5, bj = blockIdx.x & 31u;
  __shared__ float SA[256][16];
  __shared__ float SB[256][16];
  const unsigned t = threadIdx.x;
#pragma unroll
  for (int p = 0; p < 16; ++p) {
    unsigned e = p * 256u + t;
    unsigned k = e >> 4, c = e & 15u;
    SA[k][c] = S[k * 512u + bi * 16u + c];
    SB[k][c] = S[k * 512u + bj * 16u + c];
  }
  __syncthreads();
  const unsigned ti = t >> 4, tj = t & 15u;
  float acc = 0.f;
#pragma unroll 8
  for (int k = 0; k < 256; ++k) acc += SA[k][ti] * SB[k][tj];
  ws[OFF_G + (bi * 16u + ti) * 512u + bj * 16u + tj] = (bhalf)(acc * 0.0078125f);
}

__device__ inline bh8_t cvt8(f4_t f0, f4_t f1) {
  bh8_t r;
  r[0] = (bhalf)f0[0]; r[1] = (bhalf)f0[1]; r[2] = (bhalf)f0[2]; r[3] = (bhalf)f0[3];
  r[4] = (bhalf)f1[0]; r[5] = (bhalf)f1[1]; r[6] = (bhalf)f1[2]; r[7] = (bhalf)f1[3];
  return r;
}
__device__ inline unsigned pk2(float a, float b) {
  union { bhalf h; unsigned short s; } x, y;
  x.h = (bhalf)a; y.h = (bhalf)b;
  return (unsigned)x.s | ((unsigned)y.s << 16);
}
__device__ inline float up_lo(unsigned u) {
  union { unsigned u; float f; } t; t.u = u << 16; return t.f;
}
__device__ inline float up_hi(unsigned u) {
  union { unsigned u; float f; } t; t.u = u & 0xffff0000u; return t.f;
}

__device__ inline void gload16(const void* g, void* l) {
  __builtin_amdgcn_global_load_lds(
      (const __attribute__((address_space(1))) void*)g,
      (__attribute__((address_space(3))) void*)l, 16, 0, 0);
}

// LDS (156,160 B total):
//   V [32][520] bf16 linear  @ 0        (33,280)
//   buf b=0,1,2 {G 32 segs x 1024B ; P 8 segs x 1024B} @ 33280 + b*40960
//   R [32][128] bf16 col-rotated, ALIASES buf2's P region @ 147968 (8,192)
//   hid [32][1032] bf16 @ 0 (66,048; MLP only, aliases V+buf0)
#define SMBUF 33280u
#define BUFSZ 40960u
#define PREG  32768u
#define RBASE 147968u
#define SMEM_BYTES 156160

#define LGKM0   asm volatile("s_waitcnt lgkmcnt(0)" ::: "memory")
#define VMW(N)  asm volatile("s_waitcnt vmcnt(" #N ")" ::: "memory")
#define SCHEDB  __builtin_amdgcn_sched_barrier(0)
#define RAWBAR  __builtin_amdgcn_s_barrier()

#define ISSUE_GP(BO, KC) do {                                                   \
  _Pragma("unroll")                                                             \
  for (int i_ = 0; i_ < 4; ++i_) {                                              \
    unsigned s_ = w + 8u * i_;                                                  \
    gload16(Gb + gsb[i_] + (KC) * 64u, smem + SMBUF + (BO) + s_ * 1024u);       \
  }                                                                             \
  gload16(Pb + psb + (KC) * 64u, smem + SMBUF + (BO) + PREG + w * 1024u);       \
} while (0)

#define ISSUE_PT(BO, KC) do {                                                   \
  _Pragma("unroll")                                                             \
  for (int i_ = 0; i_ < 4; ++i_) {                                              \
    unsigned s_ = w + 8u * i_;                                                  \
    gload16(Ptb + ptsb[i_] + (KC) * 64u, smem + SMBUF + (BO) + s_ * 1024u);     \
  }                                                                             \
} while (0)

#define COMPUTE_GP(BO, T) do {                                                  \
  const bhalf* gb_ = (const bhalf*)(smem + SMBUF + (BO));                       \
  const bhalf* pb_ = gb_ + 16384u;                                              \
  bh8_t a0_ = *(const bh8_t*)(V_lds + lr * 520u + (T) * 32u + lq * 8u);         \
  bh8_t a1_ = *(const bh8_t*)(V_lds + (16u + lr) * 520u + (T) * 32u + lq * 8u); \
  _Pragma("unroll")                                                             \
  for (int nt_ = 0; nt_ < 4; ++nt_) {                                           \
    bh8_t bf_ = *(const bh8_t*)(gb_ + (16u * (4u * w + nt_) + lr) * 32u + lq * 8u);\
    dacc[nt_][0] = MFMA16(a0_, bf_, dacc[nt_][0]);                              \
    dacc[nt_][1] = MFMA16(a1_, bf_, dacc[nt_][1]);                              \
  }                                                                             \
  bh8_t pf_ = *(const bh8_t*)(pb_ + (16u * w + lr) * 32u + lq * 8u);            \
  Uacc[0] = MFMA16(a0_, pf_, Uacc[0]);                                          \
  Uacc[1] = MFMA16(a1_, pf_, Uacc[1]);                                          \
} while (0)

// R rotated: element (row, col) stored at row*128 + ((col + 8*row) & 127)
#define COMPUTE_PT(BO, C) do {                                                  \
  const bhalf* gb_ = (const bhalf*)(smem + SMBUF + (BO));                       \
  unsigned ro0_ = ((C) * 32u + lq * 8u + 8u * lr) & 127u;                       \
  bh8_t a0_ = *(const bh8_t*)(R_lds + lr * 128u + ro0_);                        \
  bh8_t a1_ = *(const bh8_t*)(R_lds + (16u + lr) * 128u + ro0_);                \
  _Pragma("unroll")                                                             \
  for (int nt_ = 0; nt_ < 4; ++nt_) {                                           \
    bh8_t bf_ = *(const bh8_t*)(gb_ + (16u * (4u * w + nt_) + lr) * 32u + lq * 8u);\
    dacc[nt_][0] = MFMA16(a0_, bf_, dacc[nt_][0]);                              \
    dacc[nt_][1] = MFMA16(a1_, bf_, dacc[nt_][1]);                              \
  }                                                                             \
} while (0)

__global__ __launch_bounds__(512) void amn_main(
    const float* __restrict__ input, const float* __restrict__ Vin,
    const float* __restrict__ b1, const float* __restrict__ b2,
    const int* __restrict__ niter_p,
    const bhalf* __restrict__ ws, float* __restrict__ out) {

  const unsigned tid = threadIdx.x;
  const unsigned w  = tid >> 6;    // wave 0..7
  const unsigned l  = tid & 63u;
  const unsigned lq = l >> 4;      // 0..3
  const unsigned lr = l & 15u;     // 0..15
  const unsigned row0 = blockIdx.x * 32u;
  const unsigned rq  = l >> 2;         // staging: row-in-seg 0..15
  const unsigned c16 = (l & 3u) * 16u; // staging: byte-in-row

  const bhalf* W1t = ws + OFF_W1T;
  const bhalf* W2t = ws + OFF_W2T;
  const char* Gb  = (const char*)(ws + OFF_G);
  const char* Pb  = (const char*)(ws + OFF_PINB);
  const char* Ptb = (const char*)(ws + OFF_PT);

  __shared__ __align__(16) unsigned char smem[SMEM_BYTES];
  bhalf* hid_lds = (bhalf*)smem;               // [32][1032], MLP only
  bhalf* V_lds   = (bhalf*)smem;               // [32][520]
  bhalf* R_lds   = (bhalf*)(smem + RBASE);     // [32][128] rotated

  // ===== MLP1: hidden = relu(input @ W1 + b1); wave w owns tiles 8w..8w+7 =====
  {
    f4_t hacc[2][8];
#pragma unroll
    for (int mt = 0; mt < 2; ++mt)
#pragma unroll
      for (int t = 0; t < 8; ++t) hacc[mt][t] = (f4_t)0.f;

#pragma unroll
    for (int k = 0; k < 4; ++k) {   // K = 128
      bh8_t a[2];
#pragma unroll
      for (int mt = 0; mt < 2; ++mt) {
        const float* ap = input + (row0 + 16u * mt + lr) * 128u + k * 32 + lq * 8u;
        a[mt] = cvt8(*(const f4_t*)ap, *(const f4_t*)(ap + 4));
      }
#pragma unroll
      for (int t = 0; t < 8; ++t) {
        bh8_t b = *(const bh8_t*)(W1t + (16u * (8u * w + t) + lr) * 128u + k * 32 + lq * 8u);
#pragma unroll
        for (int mt = 0; mt < 2; ++mt) hacc[mt][t] = MFMA16(a[mt], b, hacc[mt][t]);
      }
    }
#pragma unroll
    for (int t = 0; t < 8; ++t) {
      unsigned col = 16u * (8u * w + t) + lr;
      float bias = b1[col];
#pragma unroll
      for (int mt = 0; mt < 2; ++mt)
#pragma unroll
        for (int r = 0; r < 4; ++r)
          hid_lds[(16u * mt + 4u * lq + r) * 1032u + col] =
              (bhalf)fmaxf(hacc[mt][t][r] + bias, 0.f);
    }
  }
  __syncthreads();

  // ===== MLP2: V0 = hidden @ W2 + b2; wave w owns V n-tiles 4w..4w+3 =====
  f4_t Vreg[2][4];
#pragma unroll
  for (int mt = 0; mt < 2; ++mt)
#pragma unroll
    for (int n = 0; n < 4; ++n) Vreg[mt][n] = (f4_t)0.f;

#pragma unroll 2
  for (int k = 0; k < 32; ++k) {  // K = 1024
    bh8_t a[2];
#pragma unroll
    for (int mt = 0; mt < 2; ++mt)
      a[mt] = *(const bh8_t*)(hid_lds + (16u * mt + lr) * 1032u + k * 32 + lq * 8u);
#pragma unroll
    for (int n = 0; n < 4; ++n) {
      bh8_t b = *(const bh8_t*)(W2t + (16u * (4u * w + n) + lr) * 1024u + k * 32 + lq * 8u);
#pragma unroll
      for (int mt = 0; mt < 2; ++mt) Vreg[mt][n] = MFMA16(a[mt], b, Vreg[mt][n]);
    }
  }
#pragma unroll
  for (int n = 0; n < 4; ++n) {
    float bias = b2[16u * (4u * w + n) + lr];
#pragma unroll
    for (int mt = 0; mt < 2; ++mt)
#pragma unroll
      for (int r = 0; r < 4; ++r) Vreg[mt][n][r] += bias;
  }

  // ---- Vin for u-tile w, packed bf16 ----
  unsigned Vinpk[2][2];
#pragma unroll
  for (int mt = 0; mt < 2; ++mt) {
    float vi[4];
#pragma unroll
    for (int r = 0; r < 4; ++r)
      vi[r] = Vin[(row0 + 16u * mt + 4u * lq + r) * 128u + 16u * w + lr];
    Vinpk[mt][0] = pk2(vi[0], vi[1]);
    Vinpk[mt][1] = pk2(vi[2], vi[3]);
  }

  unsigned Dpk[2][4][2];
#pragma unroll
  for (int mt = 0; mt < 2; ++mt)
#pragma unroll
    for (int n = 0; n < 4; ++n) { Dpk[mt][n][0] = 0u; Dpk[mt][n][1] = 0u; }

  // staging source byte-offsets (segs w, w+8, w+16, w+24 - r9's pattern)
  unsigned gsb[4], ptsb[4];
#pragma unroll
  for (int j = 0; j < 4; ++j) {
    unsigned s = w + 8u * j;
    gsb[j]  = (16u * s + rq) * 1024u + c16;
    ptsb[j] = (16u * s + rq) * 256u + c16;
  }
  const unsigned psb = (16u * w + rq) * 1024u + c16;

  const int niter = niter_p[0];

  asm volatile("s_waitcnt vmcnt(0)" ::: "memory");  // exact counting from here
  __syncthreads();  // hid reads done; V/buf regions reusable

  // ================= momentum iterations =================
  for (int it = 0; it < niter; ++it) {
    // ---- (i) stage V (bf16, linear 520) ----
#pragma unroll
    for (int mt = 0; mt < 2; ++mt)
#pragma unroll
      for (int n = 0; n < 4; ++n) {
        unsigned col = 16u * (4u * w + n) + lr;
#pragma unroll
        for (int r = 0; r < 4; ++r)
          V_lds[(16u * mt + 4u * lq + r) * 520u + col] = (bhalf)Vreg[mt][n][r];
      }
    LGKM0; SCHEDB; RAWBAR; SCHEDB;       // BAR_B: V(it) visible; prev-iter reads done

    // prime pipeline: chunks 0,1 (10 outstanding)
    ISSUE_GP(0u, 0u);
    ISSUE_GP(BUFSZ, 1u);

    f4_t dacc[4][2];
#pragma unroll
    for (int nt = 0; nt < 4; ++nt) { dacc[nt][0] = (f4_t)0.f; dacc[nt][1] = (f4_t)0.f; }
    f4_t Uacc[2];
    Uacc[0] = (f4_t)0.f; Uacc[1] = (f4_t)0.f;

    unsigned cur = 0u;
#pragma unroll 1
    for (int t = 0; t < 14; ++t) {       // steps 0..13
      VMW(5); SCHEDB; RAWBAR; SCHEDB;    // all waves' chunk t landed
      COMPUTE_GP(cur, (unsigned)t);
      LGKM0; SCHEDB;
      unsigned o2 = cur + 2u * BUFSZ; if (o2 >= 3u * BUFSZ) o2 -= 3u * BUFSZ;
      ISSUE_GP(o2, (unsigned)t + 2u);
      cur += BUFSZ; if (cur >= 3u * BUFSZ) cur = 0u;
    }
    // step 14: compute chunk14 @ buf2; issue Pt0 -> buf1
    VMW(5); SCHEDB; RAWBAR; SCHEDB;
    COMPUTE_GP(2u * BUFSZ, 14u);
    LGKM0; SCHEDB;
    ISSUE_PT(BUFSZ, 0u);                 // outstanding: chunk15(5)+Pt0(4)=9
    // step 15: compute chunk15 @ buf0; write R; issue Pt1 -> buf2
    VMW(4); SCHEDB; RAWBAR; SCHEDB;
    COMPUTE_GP(0u, 15u);
#pragma unroll
    for (int mt = 0; mt < 2; ++mt) {
      float rv[4] = { fmaxf(Uacc[mt][0] - up_lo(Vinpk[mt][0]), 0.f),
                      fmaxf(Uacc[mt][1] - up_hi(Vinpk[mt][0]), 0.f),
                      fmaxf(Uacc[mt][2] - up_lo(Vinpk[mt][1]), 0.f),
                      fmaxf(Uacc[mt][3] - up_hi(Vinpk[mt][1]), 0.f) };
      unsigned col = 16u * w + lr;
#pragma unroll
      for (int r = 0; r < 4; ++r) {
        unsigned row = 16u * mt + 4u * lq + r;
        R_lds[row * 128u + ((col + 8u * row) & 127u)] = (bhalf)rv[r];
      }
    }
    LGKM0; SCHEDB;
    ISSUE_PT(2u * BUFSZ, 1u);            // outstanding: Pt0(4)+Pt1(4)=8
    // step 16: compute Pt0 @ buf1 (barrier also publishes R); issue Pt2 -> buf0
    VMW(4); SCHEDB; RAWBAR; SCHEDB;
    COMPUTE_PT(BUFSZ, 0u);
    LGKM0; SCHEDB;
    ISSUE_PT(0u, 2u);                    // Pt1(4)+Pt2(4)=8
    // step 17: compute Pt1 @ buf2; issue Pt3 -> buf1
    VMW(4); SCHEDB; RAWBAR; SCHEDB;
    COMPUTE_PT(2u * BUFSZ, 1u);
    LGKM0; SCHEDB;
    ISSUE_PT(BUFSZ, 3u);                 // Pt2(4)+Pt3(4)=8
    // step 18: compute Pt2 @ buf0
    VMW(4); SCHEDB; RAWBAR; SCHEDB;
    COMPUTE_PT(0u, 2u);
    // step 19: compute Pt3 @ buf1 (drain to 0)
    VMW(0); SCHEDB; RAWBAR; SCHEDB;
    COMPUTE_PT(BUFSZ, 3u);

    // ---- momentum update: dV += min(V,0)*2/512; d = .9d - .01dV; V += d ----
#pragma unroll
    for (int nt = 0; nt < 4; ++nt)
#pragma unroll
      for (int mt = 0; mt < 2; ++mt) {
        float dv0 = dacc[nt][mt][0] + fminf(Vreg[mt][nt][0], 0.f) * 0.00390625f;
        float dv1 = dacc[nt][mt][1] + fminf(Vreg[mt][nt][1], 0.f) * 0.00390625f;
        float dv2 = dacc[nt][mt][2] + fminf(Vreg[mt][nt][2], 0.f) * 0.00390625f;
        float dv3 = dacc[nt][mt][3] + fminf(Vreg[mt][nt][3], 0.f) * 0.00390625f;
        float d0 = 0.9f * up_lo(Dpk[mt][nt][0]) - 0.01f * dv0;
        float d1 = 0.9f * up_hi(Dpk[mt][nt][0]) - 0.01f * dv1;
        float d2 = 0.9f * up_lo(Dpk[mt][nt][1]) - 0.01f * dv2;
        float d3 = 0.9f * up_hi(Dpk[mt][nt][1]) - 0.01f * dv3;
        Vreg[mt][nt][0] += d0; Vreg[mt][nt][1] += d1;
        Vreg[mt][nt][2] += d2; Vreg[mt][nt][3] += d3;
        Dpk[mt][nt][0] = pk2(d0, d1);
        Dpk[mt][nt][1] = pk2(d2, d3);
      }
  }

  // ---- write final V ----
#pragma unroll
  for (int mt = 0; mt < 2; ++mt)
#pragma unroll
    for (int n = 0; n < 4; ++n) {
      unsigned col = 16u * (4u * w + n) + lr;
#pragma unroll
      for (int r = 0; r < 4; ++r)
        out[(row0 + 16u * mt + 4u * lq + r) * 512u + col] = Vreg[mt][n][r];
    }
}

extern "C" void kernel_launch(void* const* d_in, const int* in_sizes, int n_in,
                              void* d_out, int out_size, void* d_ws, size_t ws_size,
                              hipStream_t stream) {
  const float* input = (const float*)d_in[0];
  // d_in[1] = Vref (unused by reference)
  const float* Vin = (const float*)d_in[2];
  const float* W1  = (const float*)d_in[3];
  const float* b1  = (const float*)d_in[4];
  const float* W2  = (const float*)d_in[5];
  const float* b2  = (const float*)d_in[6];
  const float* S   = (const float*)d_in[7];
  const float* Pin = (const float*)d_in[8];
  const int* nit   = (const int*)d_in[9];
  bhalf* ws  = (bhalf*)d_ws;
  float* out = (float*)d_out;

  amn_prep<<<3072, 256, 0, stream>>>(W1, W2, Pin, ws);
  amn_gram<<<1024, 256, 0, stream>>>(S, ws);
  amn_main<<<1024, 512, 0, stream>>>(input, Vin, b1, b2, nit, ws, out);
}

// Round 13
// 1610.187 us; speedup vs baseline: 1.4325x; 1.0526x over previous
//
#include <hip/hip_runtime.h>

typedef __bf16 bhalf;
typedef __bf16 bh8_t __attribute__((ext_vector_type(8)));
typedef float f4_t __attribute__((ext_vector_type(4)));

#define MFMA16(A, B, C) __builtin_amdgcn_mfma_f32_16x16x32_bf16((A), (B), (C), 0, 0, 0)

// Problem: B=32768, D_IN=128, H=1024, N_FLUX=512, N_MET=256, N_IN=128
//
// ROUND 13: r12 base + wave-local self-pacing. r12's lockstep (barrier/step)
// cost ~1450cy/step of stall; wave w now stages EXACTLY the segments it reads
// (G/Pt segs 4w..4w+3, P seg w) -> recycling needs only own-wave LGKM0+vmcnt.
// 3 barriers/iter: BAR_B (V visible), BAR_R (before R-write: fixes r11's race
// where a fast wave's R-write into buf2-P clobbered a slow wave's chunk14-P),
// BAR_C (R visible). 3-deep DMA ring: issue chunk s+3 into the buf consumed at
// step s; 15 loads in flight, VMW(10) steady. Ledger: s0-13 VMW(10); s14 (9);
// s15 (8); Pt: 8,8,4,0 (drain each iter). Next-iter chunks 0,1 pre-BAR_B
// (wave-local safe); chunk 2 post-BAR_B (its P-seg overwrites R).

#define OFF_W1T  0
#define OFF_W2T  (OFF_W1T + 1024 * 128)
#define OFF_PINB (OFF_W2T + 512 * 1024)
#define OFF_PT   (OFF_PINB + 128 * 512)
#define OFF_G    (OFF_PT + 512 * 128)

__global__ __launch_bounds__(256) void amn_prep(
    const float* __restrict__ W1, const float* __restrict__ W2,
    const float* __restrict__ Pin, bhalf* __restrict__ ws) {
  unsigned i = blockIdx.x * 256u + threadIdx.x;
  if (i < 131072u) {                   // W1t[n][k] = W1[k][n]
    unsigned n = i >> 7, k = i & 127u;
    ws[OFF_W1T + i] = (bhalf)W1[k * 1024u + n];
  } else if (i < 655360u) {            // W2t[n][k] = W2[k][n]
    unsigned j = i - 131072u;
    unsigned n = j >> 10, k = j & 1023u;
    ws[OFF_W2T + j] = (bhalf)W2[k * 512u + n];
  } else if (i < 720896u) {            // Pinb = bf16(Pin)
    unsigned j = i - 655360u;
    ws[OFF_PINB + j] = (bhalf)Pin[j];
  } else if (i < 786432u) {            // Pt[n][k] = Pin[k][n] * 2/128
    unsigned j = i - 720896u;
    unsigned n = j >> 7, k = j & 127u;
    ws[OFF_PT + j] = (bhalf)(Pin[k * 512u + n] * 0.015625f);
  }
}

// G[i][j] = (2/256) * sum_k S[k][i]*S[k][j]
__global__ __launch_bounds__(256) void amn_gram(
    const float* __restrict__ S, bhalf* __restrict__ ws) {
  const unsigned bi = blockIdx.x >> 5, bj = blockIdx.x & 31u;
  __shared__ float SA[256][16];
  __shared__ float SB[256][16];
  const unsigned t = threadIdx.x;
#pragma unroll
  for (int p = 0; p < 16; ++p) {
    unsigned e = p * 256u + t;
    unsigned k = e >> 4, c = e & 15u;
    SA[k][c] = S[k * 512u + bi * 16u + c];
    SB[k][c] = S[k * 512u + bj * 16u + c];
  }
  __syncthreads();
  const unsigned ti = t >> 4, tj = t & 15u;
  float acc = 0.f;
#pragma unroll 8
  for (int k = 0; k < 256; ++k) acc += SA[k][ti] * SB[k][tj];
  ws[OFF_G + (bi * 16u + ti) * 512u + bj * 16u + tj] = (bhalf)(acc * 0.0078125f);
}

__device__ inline bh8_t cvt8(f4_t f0, f4_t f1) {
  bh8_t r;
  r[0] = (bhalf)f0[0]; r[1] = (bhalf)f0[1]; r[2] = (bhalf)f0[2]; r[3] = (bhalf)f0[3];
  r[4] = (bhalf)f1[0]; r[5] = (bhalf)f1[1]; r[6] = (bhalf)f1[2]; r[7] = (bhalf)f1[3];
  return r;
}
__device__ inline unsigned pk2(float a, float b) {
  union { bhalf h; unsigned short s; } x, y;
  x.h = (bhalf)a; y.h = (bhalf)b;
  return (unsigned)x.s | ((unsigned)y.s << 16);
}
__device__ inline float up_lo(unsigned u) {
  union { unsigned u; float f; } t; t.u = u << 16; return t.f;
}
__device__ inline float up_hi(unsigned u) {
  union { unsigned u; float f; } t; t.u = u & 0xffff0000u; return t.f;
}

__device__ inline void gload16(const void* g, void* l) {
  __builtin_amdgcn_global_load_lds(
      (const __attribute__((address_space(1))) void*)g,
      (__attribute__((address_space(3))) void*)l, 16, 0, 0);
}

// LDS (156,160 B total; same map as r12):
//   V [32][520] bf16 linear  @ 0        (33,280)
//   buf b=0,1,2 {G 32 segs x 1024B ; P 8 segs x 1024B} @ 33280 + b*40960
//   R [32][128] bf16 col-rotated, ALIASES buf2's P region @ 147968 (8,192)
//   hid [32][1032] bf16 @ 0 (66,048; MLP only, aliases V+buf0)
#define SMBUF 33280u
#define BUFSZ 40960u
#define PREG  32768u
#define RBASE 147968u
#define SMEM_BYTES 156160

#define LGKM0   asm volatile("s_waitcnt lgkmcnt(0)" ::: "memory")
#define VMW(N)  asm volatile("s_waitcnt vmcnt(" #N ")" ::: "memory")
#define SCHEDB  __builtin_amdgcn_sched_barrier(0)
#define RAWBAR  __builtin_amdgcn_s_barrier()

// WAVE-LOCAL staging: wave w stages segs 4w..4w+3 (the ones it reads).
#define ISSUE_GP(BO, KC) do {                                                   \
  _Pragma("unroll")                                                             \
  for (int i_ = 0; i_ < 4; ++i_)                                                \
    gload16(Gb + gsb[i_] + (KC) * 64u,                                          \
            smem + SMBUF + (BO) + (4u * w + i_) * 1024u);                       \
  gload16(Pb + psb + (KC) * 64u, smem + SMBUF + (BO) + PREG + w * 1024u);       \
} while (0)

#define ISSUE_PT(BO, KC) do {                                                   \
  _Pragma("unroll")                                                             \
  for (int i_ = 0; i_ < 4; ++i_)                                                \
    gload16(Ptb + ptsb[i_] + (KC) * 64u,                                        \
            smem + SMBUF + (BO) + (4u * w + i_) * 1024u);                       \
} while (0)

#define COMPUTE_GP(BO, T) do {                                                  \
  const bhalf* gb_ = (const bhalf*)(smem + SMBUF + (BO));                       \
  const bhalf* pb_ = gb_ + 16384u;                                              \
  bh8_t a0_ = *(const bh8_t*)(V_lds + lr * 520u + (T) * 32u + lq * 8u);         \
  bh8_t a1_ = *(const bh8_t*)(V_lds + (16u + lr) * 520u + (T) * 32u + lq * 8u); \
  _Pragma("unroll")                                                             \
  for (int nt_ = 0; nt_ < 4; ++nt_) {                                           \
    bh8_t bf_ = *(const bh8_t*)(gb_ + (16u * (4u * w + nt_) + lr) * 32u + lq * 8u);\
    dacc[nt_][0] = MFMA16(a0_, bf_, dacc[nt_][0]);                              \
    dacc[nt_][1] = MFMA16(a1_, bf_, dacc[nt_][1]);                              \
  }                                                                             \
  bh8_t pf_ = *(const bh8_t*)(pb_ + (16u * w + lr) * 32u + lq * 8u);            \
  Uacc[0] = MFMA16(a0_, pf_, Uacc[0]);                                          \
  Uacc[1] = MFMA16(a1_, pf_, Uacc[1]);                                          \
} while (0)

// R rotated: element (row, col) stored at row*128 + ((col + 8*row) & 127)
#define COMPUTE_PT(BO, C) do {                                                  \
  const bhalf* gb_ = (const bhalf*)(smem + SMBUF + (BO));                       \
  unsigned ro0_ = ((C) * 32u + lq * 8u + 8u * lr) & 127u;                       \
  bh8_t a0_ = *(const bh8_t*)(R_lds + lr * 128u + ro0_);                        \
  bh8_t a1_ = *(const bh8_t*)(R_lds + (16u + lr) * 128u + ro0_);                \
  _Pragma("unroll")                                                             \
  for (int nt_ = 0; nt_ < 4; ++nt_) {                                           \
    bh8_t bf_ = *(const bh8_t*)(gb_ + (16u * (4u * w + nt_) + lr) * 32u + lq * 8u);\
    dacc[nt_][0] = MFMA16(a0_, bf_, dacc[nt_][0]);                              \
    dacc[nt_][1] = MFMA16(a1_, bf_, dacc[nt_][1]);                              \
  }                                                                             \
} while (0)

__global__ __launch_bounds__(512) void amn_main(
    const float* __restrict__ input, const float* __restrict__ Vin,
    const float* __restrict__ b1, const float* __restrict__ b2,
    const int* __restrict__ niter_p,
    const bhalf* __restrict__ ws, float* __restrict__ out) {

  const unsigned tid = threadIdx.x;
  const unsigned w  = tid >> 6;    // wave 0..7
  const unsigned l  = tid & 63u;
  const unsigned lq = l >> 4;      // 0..3
  const unsigned lr = l & 15u;     // 0..15
  const unsigned row0 = blockIdx.x * 32u;
  const unsigned rq  = l >> 2;         // staging: row-in-seg 0..15
  const unsigned c16 = (l & 3u) * 16u; // staging: byte-in-row

  const bhalf* W1t = ws + OFF_W1T;
  const bhalf* W2t = ws + OFF_W2T;
  const char* Gb  = (const char*)(ws + OFF_G);
  const char* Pb  = (const char*)(ws + OFF_PINB);
  const char* Ptb = (const char*)(ws + OFF_PT);

  __shared__ __align__(16) unsigned char smem[SMEM_BYTES];
  bhalf* hid_lds = (bhalf*)smem;               // [32][1032], MLP only
  bhalf* V_lds   = (bhalf*)smem;               // [32][520]
  bhalf* R_lds   = (bhalf*)(smem + RBASE);     // [32][128] rotated

  // ===== MLP1: hidden = relu(input @ W1 + b1); wave w owns tiles 8w..8w+7 =====
  {
    f4_t hacc[2][8];
#pragma unroll
    for (int mt = 0; mt < 2; ++mt)
#pragma unroll
      for (int t = 0; t < 8; ++t) hacc[mt][t] = (f4_t)0.f;

#pragma unroll
    for (int k = 0; k < 4; ++k) {   // K = 128
      bh8_t a[2];
#pragma unroll
      for (int mt = 0; mt < 2; ++mt) {
        const float* ap = input + (row0 + 16u * mt + lr) * 128u + k * 32 + lq * 8u;
        a[mt] = cvt8(*(const f4_t*)ap, *(const f4_t*)(ap + 4));
      }
#pragma unroll
      for (int t = 0; t < 8; ++t) {
        bh8_t b = *(const bh8_t*)(W1t + (16u * (8u * w + t) + lr) * 128u + k * 32 + lq * 8u);
#pragma unroll
        for (int mt = 0; mt < 2; ++mt) hacc[mt][t] = MFMA16(a[mt], b, hacc[mt][t]);
      }
    }
#pragma unroll
    for (int t = 0; t < 8; ++t) {
      unsigned col = 16u * (8u * w + t) + lr;
      float bias = b1[col];
#pragma unroll
      for (int mt = 0; mt < 2; ++mt)
#pragma unroll
        for (int r = 0; r < 4; ++r)
          hid_lds[(16u * mt + 4u * lq + r) * 1032u + col] =
              (bhalf)fmaxf(hacc[mt][t][r] + bias, 0.f);
    }
  }
  __syncthreads();

  // ===== MLP2: V0 = hidden @ W2 + b2; wave w owns V n-tiles 4w..4w+3 =====
  f4_t Vreg[2][4];
#pragma unroll
  for (int mt = 0; mt < 2; ++mt)
#pragma unroll
    for (int n = 0; n < 4; ++n) Vreg[mt][n] = (f4_t)0.f;

#pragma unroll 2
  for (int k = 0; k < 32; ++k) {  // K = 1024
    bh8_t a[2];
#pragma unroll
    for (int mt = 0; mt < 2; ++mt)
      a[mt] = *(const bh8_t*)(hid_lds + (16u * mt + lr) * 1032u + k * 32 + lq * 8u);
#pragma unroll
    for (int n = 0; n < 4; ++n) {
      bh8_t b = *(const bh8_t*)(W2t + (16u * (4u * w + n) + lr) * 1024u + k * 32 + lq * 8u);
#pragma unroll
      for (int mt = 0; mt < 2; ++mt) Vreg[mt][n] = MFMA16(a[mt], b, Vreg[mt][n]);
    }
  }
#pragma unroll
  for (int n = 0; n < 4; ++n) {
    float bias = b2[16u * (4u * w + n) + lr];
#pragma unroll
    for (int mt = 0; mt < 2; ++mt)
#pragma unroll
      for (int r = 0; r < 4; ++r) Vreg[mt][n][r] += bias;
  }

  // ---- Vin for u-tile w, packed bf16 ----
  unsigned Vinpk[2][2];
#pragma unroll
  for (int mt = 0; mt < 2; ++mt) {
    float vi[4];
#pragma unroll
    for (int r = 0; r < 4; ++r)
      vi[r] = Vin[(row0 + 16u * mt + 4u * lq + r) * 128u + 16u * w + lr];
    Vinpk[mt][0] = pk2(vi[0], vi[1]);
    Vinpk[mt][1] = pk2(vi[2], vi[3]);
  }

  unsigned Dpk[2][4][2];
#pragma unroll
  for (int mt = 0; mt < 2; ++mt)
#pragma unroll
    for (int n = 0; n < 4; ++n) { Dpk[mt][n][0] = 0u; Dpk[mt][n][1] = 0u; }

  // staging source byte-offsets — WAVE-LOCAL segs 4w..4w+3
  unsigned gsb[4], ptsb[4];
#pragma unroll
  for (int j = 0; j < 4; ++j) {
    unsigned s = 4u * w + j;
    gsb[j]  = (16u * s + rq) * 1024u + c16;
    ptsb[j] = (16u * s + rq) * 256u + c16;
  }
  const unsigned psb = (16u * w + rq) * 1024u + c16;

  const int niter = niter_p[0];

  asm volatile("s_waitcnt vmcnt(0)" ::: "memory");  // exact counting from here
  __syncthreads();  // hid reads done; V/buf regions reusable

  // ================= momentum iterations =================
  for (int it = 0; it < niter; ++it) {
    // ---- stage V (bf16, linear 520) ----
#pragma unroll
    for (int mt = 0; mt < 2; ++mt)
#pragma unroll
      for (int n = 0; n < 4; ++n) {
        unsigned col = 16u * (4u * w + n) + lr;
#pragma unroll
        for (int r = 0; r < 4; ++r)
          V_lds[(16u * mt + 4u * lq + r) * 520u + col] = (bhalf)Vreg[mt][n][r];
      }
    LGKM0; SCHEDB;
    // pre-barrier prefetch (wave-local bufs; safe vs other waves' Pt reads)
    ISSUE_GP(0u, 0u);
    ISSUE_GP(BUFSZ, 1u);
    SCHEDB; RAWBAR; SCHEDB;            // BAR_B: V(it) visible; R(it-1) reads done
    ISSUE_GP(2u * BUFSZ, 2u);          // buf2-P aliases R -> post-barrier only
    // outstanding: 15

    f4_t dacc[4][2];
#pragma unroll
    for (int nt = 0; nt < 4; ++nt) { dacc[nt][0] = (f4_t)0.f; dacc[nt][1] = (f4_t)0.f; }
    f4_t Uacc[2];
    Uacc[0] = (f4_t)0.f; Uacc[1] = (f4_t)0.f;

    // ---- G+P phase, self-paced, 3-deep ring (issue s+3 into buf just read) ----
    unsigned cur = 0u;
#pragma unroll 1
    for (int t = 0; t < 13; ++t) {     // steps 0..12
      VMW(10); SCHEDB;                 // own chunk t landed
      COMPUTE_GP(cur, (unsigned)t);
      LGKM0; SCHEDB;
      ISSUE_GP(cur, (unsigned)t + 3u);
      cur += BUFSZ; if (cur >= 3u * BUFSZ) cur = 0u;
    }
    // step 13: compute 13 @ buf1; issue Pt0 -> buf1
    VMW(10); SCHEDB; COMPUTE_GP(BUFSZ, 13u); LGKM0; SCHEDB; ISSUE_PT(BUFSZ, 0u);
    // step 14: compute 14 @ buf2; issue Pt1 -> buf2 (G region only; R untouched)
    VMW(9); SCHEDB; COMPUTE_GP(2u * BUFSZ, 14u); LGKM0; SCHEDB; ISSUE_PT(2u * BUFSZ, 1u);
    // step 15: compute 15 @ buf0; issue Pt2 -> buf0
    VMW(8); SCHEDB; COMPUTE_GP(0u, 15u); LGKM0; SCHEDB; ISSUE_PT(0u, 2u);

    // ---- R = relu(U - Vin); BAR_R first: all waves past their chunk14-P read
    SCHEDB; RAWBAR; SCHEDB;            // BAR_R (fixes r11's race)
#pragma unroll
    for (int mt = 0; mt < 2; ++mt) {
      float rv[4] = { fmaxf(Uacc[mt][0] - up_lo(Vinpk[mt][0]), 0.f),
                      fmaxf(Uacc[mt][1] - up_hi(Vinpk[mt][0]), 0.f),
                      fmaxf(Uacc[mt][2] - up_lo(Vinpk[mt][1]), 0.f),
                      fmaxf(Uacc[mt][3] - up_hi(Vinpk[mt][1]), 0.f) };
      unsigned col = 16u * w + lr;
#pragma unroll
      for (int r = 0; r < 4; ++r) {
        unsigned row = 16u * mt + 4u * lq + r;
        R_lds[row * 128u + ((col + 8u * row) & 127u)] = (bhalf)rv[r];
      }
    }
    LGKM0; SCHEDB; RAWBAR; SCHEDB;     // BAR_C: R visible

    // ---- Pt phase, self-paced ----
    // step 16: compute Pt0 @ buf1; issue Pt3 -> buf1
    VMW(8); SCHEDB; COMPUTE_PT(BUFSZ, 0u); LGKM0; SCHEDB; ISSUE_PT(BUFSZ, 3u);
    // step 17: compute Pt1 @ buf2 (R @ buf2-P still intact)
    VMW(8); SCHEDB; COMPUTE_PT(2u * BUFSZ, 1u);
    // step 18: compute Pt2 @ buf0
    VMW(4); SCHEDB; COMPUTE_PT(0u, 2u);
    // step 19: compute Pt3 @ buf1 (drain to 0)
    VMW(0); SCHEDB; COMPUTE_PT(BUFSZ, 3u);

    // ---- momentum update: dV += min(V,0)*2/512; d = .9d - .01dV; V += d ----
#pragma unroll
    for (int nt = 0; nt < 4; ++nt)
#pragma unroll
      for (int mt = 0; mt < 2; ++mt) {
        float dv0 = dacc[nt][mt][0] + fminf(Vreg[mt][nt][0], 0.f) * 0.00390625f;
        float dv1 = dacc[nt][mt][1] + fminf(Vreg[mt][nt][1], 0.f) * 0.00390625f;
        float dv2 = dacc[nt][mt][2] + fminf(Vreg[mt][nt][2], 0.f) * 0.00390625f;
        float dv3 = dacc[nt][mt][3] + fminf(Vreg[mt][nt][3], 0.f) * 0.00390625f;
        float d0 = 0.9f * up_lo(Dpk[mt][nt][0]) - 0.01f * dv0;
        float d1 = 0.9f * up_hi(Dpk[mt][nt][0]) - 0.01f * dv1;
        float d2 = 0.9f * up_lo(Dpk[mt][nt][1]) - 0.01f * dv2;
        float d3 = 0.9f * up_hi(Dpk[mt][nt][1]) - 0.01f * dv3;
        Vreg[mt][nt][0] += d0; Vreg[mt][nt][1] += d1;
        Vreg[mt][nt][2] += d2; Vreg[mt][nt][3] += d3;
        Dpk[mt][nt][0] = pk2(d0, d1);
        Dpk[mt][nt][1] = pk2(d2, d3);
      }
  }

  // ---- write final V (pipeline drained at step 19 of last iter) ----
#pragma unroll
  for (int mt = 0; mt < 2; ++mt)
#pragma unroll
    for (int n = 0; n < 4; ++n) {
      unsigned col = 16u * (4u * w + n) + lr;
#pragma unroll
      for (int r = 0; r < 4; ++r)
        out[(row0 + 16u * mt + 4u * lq + r) * 512u + col] = Vreg[mt][n][r];
    }
}

extern "C" void kernel_launch(void* const* d_in, const int* in_sizes, int n_in,
                              void* d_out, int out_size, void* d_ws, size_t ws_size,
                              hipStream_t stream) {
  const float* input = (const float*)d_in[0];
  // d_in[1] = Vref (unused by reference)
  const float* Vin = (const float*)d_in[2];
  const float* W1  = (const float*)d_in[3];
  const float* b1  = (const float*)d_in[4];
  const float* W2  = (const float*)d_in[5];
  const float* b2  = (const float*)d_in[6];
  const float* S   = (const float*)d_in[7];
  const float* Pin = (const float*)d_in[8];
  const int* nit   = (const int*)d_in[9];
  bhalf* ws  = (bhalf*)d_ws;
  float* out = (float*)d_out;

  amn_prep<<<3072, 256, 0, stream>>>(W1, W2, Pin, ws);
  amn_gram<<<1024, 256, 0, stream>>>(S, ws);
  amn_main<<<1024, 512, 0, stream>>>(input, Vin, b1, b2, nit, ws, out);
}